// Round 4
// baseline (564.733 us; speedup 1.0000x reference)
//
#include <hip/hip_runtime.h>

#define NEG_SLOPE 0.2f

// Fixed-point scales (identical across all versions -> bit-identical integer sums).
// Accumulator u64: hi 32 = num (s16.15, two's complement), lo 32 = den (u13.19).
// den total < 2^32 (worst case ~3000 edges * e^8-bounded? no: logits O(1), ~6400*2^19
// = 3.4e9 < 2^32 even for max in-degree observed ~ deg*e^~1) -> no carry into hi word,
// including while summing the 8 per-XCD replicas (partial sums <= total).
#define DEN_SCALE 524288.0f     // 2^19
#define NUM_SCALE 32768.0f      // 2^15
#define INV_DEN_SCALE (1.0f / 524288.0f)
#define INV_NUM_SCALE (1.0f / 32768.0f)

#define NREP 8                  // one accumulator replica per XCD (MI355X: 8 XCDs)

typedef float v4f __attribute__((ext_vector_type(4)));
typedef int   v4i __attribute__((ext_vector_type(4)));
typedef unsigned long long u64;
typedef unsigned int u32;

// -------- Kernel 1: x[row] = dot(F[row,:], W) (one 64-lane wave per row) --------
__global__ void gemv_rowdot(const float* __restrict__ F, const float* __restrict__ W,
                            float* __restrict__ x, int n, int d) {
    int wave = (blockIdx.x * blockDim.x + threadIdx.x) >> 6;
    int lane = threadIdx.x & 63;
    if (wave >= n) return;
    const v4f* f4 = (const v4f*)(F + (size_t)wave * d);
    const v4f* w4 = (const v4f*)W;
    int nv = d >> 2;
    float s = 0.f;
    #pragma unroll 2
    for (int k = lane; k < nv; k += 64) {
        v4f a = __builtin_nontemporal_load(&f4[k]);   // F streamed once: keep L2 for x
        v4f b = w4[k];
        s += a.x * b.x + a.y * b.y + a.z * b.z + a.w * b.w;
    }
    #pragma unroll
    for (int off = 32; off; off >>= 1) s += __shfl_down(s, off, 64);
    if (lane == 0) x[wave] = s;
}

// ---- per-edge body: exp(lrelu) -> ONE u64 fixed-point atomic, WORKGROUP scope ----
// Workgroup scope emits global_atomic_add_x2 with no system-coherence bits -> the RMW
// executes in the issuing XCD's local L2 (no 32B write-through to the coherence point).
// Correct because each XCD only ever touches its own replica (selected by XCC_ID), and
// all CUs of one XCD share that L2's atomic unit. Cross-kernel visibility comes from
// the end-of-dispatch L2 writeback (same mechanism that carries x across kernels).
__device__ __forceinline__ void edge_one_wg(float xs, float xd, float as, float ad,
                                            int d, u64* __restrict__ acc) {
    float v = xs * as + xd * ad;
    float logit = v > 0.f ? v : NEG_SLOPE * v;
    float e = __expf(logit);
    u32 den_fx = (u32)__float2int_rn(e * DEN_SCALE);
    int num_fx = __float2int_rn(e * xs * NUM_SCALE);
    u64 upd = ((u64)(u32)num_fx << 32) | (u64)den_fx;
    __hip_atomic_fetch_add(acc + d, upd, __ATOMIC_RELAXED, __HIP_MEMORY_SCOPE_WORKGROUP);
}

// -------- Kernel 2: 4 edges/thread, per-XCD replica accumulation --------
__global__ __launch_bounds__(256)
void edge_atomic_xcd(const int* __restrict__ ei, const float* __restrict__ x,
                     const float* __restrict__ att_src_p,
                     const float* __restrict__ att_dst_p,
                     u64* __restrict__ rep, size_t repstride, int nedges) {
    u32 xcc;
    asm volatile("s_getreg_b32 %0, hwreg(HW_REG_XCC_ID)" : "=s"(xcc));
    u64* acc = rep + (size_t)(xcc & (NREP - 1)) * repstride;

    int nq = (nedges + 3) >> 2;
    int i = blockIdx.x * blockDim.x + threadIdx.x;
    if (i >= nq) return;
    float as = *att_src_p, ad = *att_dst_p;

    if ((nedges & 3) == 0) {                      // aligned vector path (the real shape)
        const v4i* s4 = (const v4i*)ei;
        const v4i* d4 = (const v4i*)(ei + nedges);
        v4i s = __builtin_nontemporal_load(&s4[i]);   // edge stream: don't evict x/acc
        v4i d = __builtin_nontemporal_load(&d4[i]);
        // all 8 gathers issued before compute -> max MLP
        float xs0 = x[s.x], xs1 = x[s.y], xs2 = x[s.z], xs3 = x[s.w];
        float xd0 = x[d.x], xd1 = x[d.y], xd2 = x[d.z], xd3 = x[d.w];
        edge_one_wg(xs0, xd0, as, ad, d.x, acc);
        edge_one_wg(xs1, xd1, as, ad, d.y, acc);
        edge_one_wg(xs2, xd2, as, ad, d.z, acc);
        edge_one_wg(xs3, xd3, as, ad, d.w, acc);
    } else {
        int base = i << 2;
        int lim = min(base + 4, nedges);
        for (int t = base; t < lim; ++t) {
            int s = ei[t], dd = ei[nedges + t];
            edge_one_wg(x[s], x[dd], as, ad, dd, acc);
        }
    }
}

// -------- Kernel 3: out = (sum_k rep[k] + self-loop) -> softmax-normalized --------
__global__ void finalize_rep(const u64* __restrict__ rep, size_t repstride,
                             const float* __restrict__ x,
                             const float* __restrict__ att_src_p,
                             const float* __restrict__ att_dst_p,
                             const float* __restrict__ bias, float* __restrict__ out,
                             int n) {
    int i = blockIdx.x * blockDim.x + threadIdx.x;
    if (i >= n) return;
    u64 t = 0ull;
    #pragma unroll
    for (int k = 0; k < NREP; ++k) t += rep[(size_t)k * repstride + i];
    float xi = x[i];
    float v = xi * (*att_src_p + *att_dst_p);       // self-loop logit
    float logit = v > 0.f ? v : NEG_SLOPE * v;
    float es = __expf(logit);
    float num = (float)(int)(t >> 32) * INV_NUM_SCALE;
    float den = (float)(u32)(t & 0xFFFFFFFFull) * INV_DEN_SCALE;
    out[i] = (num + es * xi) / (den + es) + *bias;
}

// ================= fallback (ws too small): device-scope single-acc path ===========
__device__ __forceinline__ void edge_one_dev(float xs, float xd, float as, float ad,
                                             int d, u64* __restrict__ acc) {
    float v = xs * as + xd * ad;
    float logit = v > 0.f ? v : NEG_SLOPE * v;
    float e = __expf(logit);
    u32 den_fx = (u32)__float2int_rn(e * DEN_SCALE);
    int num_fx = __float2int_rn(e * xs * NUM_SCALE);
    atomicAdd(&acc[d], ((u64)(u32)num_fx << 32) | (u64)den_fx);
}

__global__ void edge_accum1(const int* __restrict__ ei, const float* __restrict__ x,
                            const float* __restrict__ att_src_p,
                            const float* __restrict__ att_dst_p,
                            u64* __restrict__ acc, int nedges) {
    int i = blockIdx.x * blockDim.x + threadIdx.x;
    if (i >= nedges) return;
    int s = ei[i], d = ei[nedges + i];
    edge_one_dev(x[s], x[d], *att_src_p, *att_dst_p, d, acc);
}

__global__ void finalize_atomic(const u64* __restrict__ acc, const float* __restrict__ x,
                                const float* __restrict__ att_src_p,
                                const float* __restrict__ att_dst_p,
                                const float* __restrict__ bias, float* __restrict__ out,
                                int n) {
    int i = blockIdx.x * blockDim.x + threadIdx.x;
    if (i >= n) return;
    float xi = x[i];
    float v = xi * (*att_src_p + *att_dst_p);
    float logit = v > 0.f ? v : NEG_SLOPE * v;
    float es = __expf(logit);
    u64 a = acc[i];
    float num = (float)(int)(a >> 32) * INV_NUM_SCALE;
    float den = (float)(u32)(a & 0xFFFFFFFFull) * INV_DEN_SCALE;
    out[i] = (num + es * xi) / (den + es) + *bias;
}

extern "C" void kernel_launch(void* const* d_in, const int* in_sizes, int n_in,
                              void* d_out, int out_size, void* d_ws, size_t ws_size,
                              hipStream_t stream) {
    const float* F       = (const float*)d_in[0];
    const int*   ei      = (const int*)d_in[1];
    const float* W       = (const float*)d_in[2];
    const float* att_src = (const float*)d_in[3];
    const float* att_dst = (const float*)d_in[4];
    const float* bias    = (const float*)d_in[5];
    float* out = (float*)d_out;

    int d = in_sizes[2];              // 512
    int n = in_sizes[0] / d;          // 100000
    int e = in_sizes[1] / 2;          // 6400000

    // workspace: x [n floats], then NREP u64 replicas of the accumulator
    size_t off_rep = ((size_t)n * 4 + 7) & ~(size_t)7;
    size_t repstride = (size_t)n;                         // u64 elements per replica
    size_t needed_fast = off_rep + (size_t)NREP * repstride * 8;
    size_t needed_slow = off_rep + repstride * 8;

    float* x  = (float*)d_ws;
    u64* rep  = (u64*)((char*)d_ws + off_rep);

    if (needed_fast <= ws_size && n > 0) {
        // zero all replicas (ws is re-poisoned 0xAA before every timed launch)
        (void)hipMemsetAsync(rep, 0, (size_t)NREP * repstride * 8, stream);
        gemv_rowdot<<<(n + 3) / 4, 256, 0, stream>>>(F, W, x, n, d);
        if (e > 0) {
            int nq = (e + 3) >> 2;
            edge_atomic_xcd<<<(nq + 255) / 256, 256, 0, stream>>>(
                ei, x, att_src, att_dst, rep, repstride, e);
        }
        finalize_rep<<<(n + 255) / 256, 256, 0, stream>>>(rep, repstride, x, att_src,
                                                          att_dst, bias, out, n);
    } else if (needed_slow <= ws_size && n > 0) {
        (void)hipMemsetAsync(rep, 0, repstride * 8, stream);
        gemv_rowdot<<<(n + 3) / 4, 256, 0, stream>>>(F, W, x, n, d);
        if (e > 0) {
            edge_accum1<<<(e + 255) / 256, 256, 0, stream>>>(ei, x, att_src, att_dst,
                                                             rep, e);
        }
        finalize_atomic<<<(n + 255) / 256, 256, 0, stream>>>(rep, x, att_src, att_dst,
                                                             bias, out, n);
    }
}

// Round 5
// 363.721 us; speedup vs baseline: 1.5527x; 1.5527x over previous
//
#include <hip/hip_runtime.h>

#define NEG_SLOPE 0.2f

// Fixed-point scales (identical across all versions -> bit-identical integer sums).
// Accumulator u64: hi 32 = num (s16.15, two's complement), lo 32 = den (u13.19).
#define DEN_SCALE 524288.0f     // 2^19
#define NUM_SCALE 32768.0f      // 2^15
#define INV_DEN_SCALE (1.0f / 524288.0f)
#define INV_NUM_SCALE (1.0f / 32768.0f)

// Binning geometry
#define RBITS 12
#define RSZ   4096
#define MAXNB 64                // n <= 262144 bins-wise; 4B packing needs n <= 2^20
#define SSUB  20                // 25 bins * 20 = 500 blocks -> ~2 blocks/CU, one pass
#define EPT   16                // edges per thread, phase 1
#define P1BLK 256
#define CHUNK (P1BLK * EPT)     // 4096 edges per scatter block
#define P2BLK 1024

typedef float v4f __attribute__((ext_vector_type(4)));
typedef int   v4i __attribute__((ext_vector_type(4)));
typedef unsigned long long u64;
typedef unsigned int u32;

// -------- standalone gemv (fallback path) --------
__global__ void gemv_rowdot(const float* __restrict__ F, const float* __restrict__ W,
                            float* __restrict__ x, int n, int d) {
    int wave = (blockIdx.x * blockDim.x + threadIdx.x) >> 6;
    int lane = threadIdx.x & 63;
    if (wave >= n) return;
    const v4f* f4 = (const v4f*)(F + (size_t)wave * d);
    const v4f* w4 = (const v4f*)W;
    int nv = d >> 2;
    float s = 0.f;
    #pragma unroll 2
    for (int k = lane; k < nv; k += 64) {
        v4f a = __builtin_nontemporal_load(&f4[k]);
        v4f b = w4[k];
        s += a.x * b.x + a.y * b.y + a.z * b.z + a.w * b.w;
    }
    #pragma unroll
    for (int off = 32; off; off >>= 1) s += __shfl_down(s, off, 64);
    if (lane == 0) x[wave] = s;
}

// -------- Fused kernel: scatter blocks first (no x dependency), gemv blocks after.
// Scatter payload is 4B: {src:20 | dst_low:12}. All float work deferred to phase 2.
// Overflow (adversarial dst skew only) appends {src,dst} to a list consumed by phase 2.
__global__ __launch_bounds__(P1BLK)
void gemv_and_scatter(const float* __restrict__ F, const float* __restrict__ W,
                      float* __restrict__ x, int n, int d,
                      const int* __restrict__ ei, u32* __restrict__ binbuf,
                      u32* __restrict__ cnt, u64* __restrict__ ovf,
                      int nedges, int nb, int capb, int nsblk, u32 ovfcap) {
    if ((int)blockIdx.x >= nsblk) {
        // ---------------- gemv part: one wave per row ----------------
        int gblk = (int)blockIdx.x - nsblk;
        int wave = gblk * 4 + ((int)threadIdx.x >> 6);
        int lane = threadIdx.x & 63;
        if (wave >= n) return;
        const v4f* f4 = (const v4f*)(F + (size_t)wave * d);
        const v4f* w4 = (const v4f*)W;
        int nv = d >> 2;
        float s = 0.f;
        #pragma unroll 2
        for (int k = lane; k < nv; k += 64) {
            v4f a = __builtin_nontemporal_load(&f4[k]);
            v4f b = w4[k];
            s += a.x * b.x + a.y * b.y + a.z * b.z + a.w * b.w;
        }
        #pragma unroll
        for (int off = 32; off; off >>= 1) s += __shfl_down(s, off, 64);
        if (lane == 0) x[wave] = s;
        return;
    }
    // ---------------- scatter part ----------------
    __shared__ u32 lhist[MAXNB];
    __shared__ u32 lbase[MAXNB];
    const int tid = threadIdx.x;
    for (int b = tid; b < nb; b += P1BLK) lhist[b] = 0;
    __syncthreads();

    const long long base_e = (long long)blockIdx.x * CHUNK + (long long)tid * EPT;

    int se[EPT], de[EPT];
    if (((nedges & 3) == 0) && (base_e + EPT <= nedges)) {
        const v4i* sp = (const v4i*)(ei + base_e);
        const v4i* dp = (const v4i*)(ei + (size_t)nedges + base_e);
        #pragma unroll
        for (int q = 0; q < EPT / 4; ++q) {
            v4i a = __builtin_nontemporal_load(&sp[q]);
            v4i b = __builtin_nontemporal_load(&dp[q]);
            se[4 * q + 0] = a.x; se[4 * q + 1] = a.y;
            se[4 * q + 2] = a.z; se[4 * q + 3] = a.w;
            de[4 * q + 0] = b.x; de[4 * q + 1] = b.y;
            de[4 * q + 2] = b.z; de[4 * q + 3] = b.w;
        }
    } else {
        #pragma unroll
        for (int t = 0; t < EPT; ++t) {
            long long idx = base_e + t;
            if (idx < nedges) { se[t] = ei[idx]; de[t] = ei[(size_t)nedges + idx]; }
            else { se[t] = -1; de[t] = -1; }
        }
    }

    u32 pk[EPT], rk[EPT]; int bn[EPT];
    #pragma unroll
    for (int t = 0; t < EPT; ++t) {
        if (se[t] >= 0) {
            bn[t] = de[t] >> RBITS;
            pk[t] = ((u32)se[t] << RBITS) | (u32)(de[t] & (RSZ - 1));
            rk[t] = atomicAdd(&lhist[bn[t]], 1u);      // LDS arrival rank
        } else {
            bn[t] = -1;
        }
    }
    __syncthreads();
    if (tid < nb) lbase[tid] = atomicAdd(&cnt[tid], lhist[tid]);   // reserve window
    __syncthreads();
    #pragma unroll
    for (int t = 0; t < EPT; ++t) {
        if (bn[t] >= 0) {
            u32 slot = lbase[bn[t]] + rk[t];
            if (slot < (u32)capb) {
                binbuf[(size_t)bn[t] * (size_t)capb + slot] = pk[t];
            } else {
                u32 os = atomicAdd(&cnt[MAXNB], 1u);   // overflow counter
                if (os < ovfcap)
                    ovf[os] = ((u64)(u32)se[t] << 32) | (u64)(u32)de[t];
            }
        }
    }
}

// -------- Phase 2: per-bin LDS accumulation. xd from LDS-staged bin slice of x,
// xs gathered from L2-resident x. u64 fixed-point LDS atomics (bit-exact sums).
// Overflow entries (normally zero) are folded in here: sub-block s of bin b handles
// list entries i == s (mod SSUB) whose dst falls in bin b.
__global__ __launch_bounds__(P2BLK)
void bin_reduce(const u32* __restrict__ binbuf, const u32* __restrict__ cnt,
                const float* __restrict__ x,
                const u64* __restrict__ ovf, u32 ovfcap,
                const float* __restrict__ att_src_p, const float* __restrict__ att_dst_p,
                u64* __restrict__ partial, int n, int capb) {
    __shared__ u64 lacc[RSZ];            // 32 KB
    __shared__ float lx[RSZ];            // 16 KB bin slice of x
    const int b = blockIdx.x / SSUB;
    const int s = blockIdx.x % SSUB;
    const int tid = threadIdx.x;
    const int base = b << RBITS;
    #pragma unroll
    for (int r = tid; r < RSZ; r += P2BLK) {
        lacc[r] = 0ull;
        int idx = base + r;
        lx[r] = (idx < n) ? x[idx] : 0.f;
    }
    __syncthreads();

    const float as = *att_src_p, ad = *att_dst_p;
    u32 cb = cnt[b];
    if (cb > (u32)capb) cb = (u32)capb;
    u32 lo = (u32)(((u64)cb * (u32)s) / SSUB);
    u32 hi = (u32)(((u64)cb * (u32)(s + 1)) / SSUB);
    const u32* src = binbuf + (size_t)b * (size_t)capb;

    // scalar helper as a lambda-free macro-ish inline
    #define PROC_ONE(p)                                                        \
        {                                                                      \
            u32 _p = (p);                                                      \
            int sj = (int)(_p >> RBITS);                                       \
            int dlow = (int)(_p & (RSZ - 1));                                  \
            float xs = x[sj];                                                  \
            float xd = lx[dlow];                                               \
            float v = xs * as + xd * ad;                                       \
            float logit = v > 0.f ? v : NEG_SLOPE * v;                         \
            float e = __expf(logit);                                           \
            u32 den = (u32)__float2int_rn(e * DEN_SCALE);                      \
            int num = __float2int_rn(e * xs * NUM_SCALE);                      \
            atomicAdd(&lacc[dlow], ((u64)(u32)num << 32) | (u64)den);          \
        }

    u32 alo = (lo + 3u) & ~3u;
    u32 ahi = hi & ~3u;
    if (ahi <= alo) {
        for (u32 k = lo + tid; k < hi; k += P2BLK) PROC_ONE(src[k]);
    } else {
        if (tid < (int)(alo - lo)) PROC_ONE(src[lo + tid]);
        const v4i* src4 = (const v4i*)(src + alo);
        u32 nvec = (ahi - alo) >> 2;
        for (u32 q = tid; q < nvec; q += P2BLK) {
            v4i pv = __builtin_nontemporal_load(&src4[q]);   // read-once stream
            u32 p0 = (u32)pv.x, p1 = (u32)pv.y, p2 = (u32)pv.z, p3 = (u32)pv.w;
            // decode all, gather all, then compute (max MLP)
            int sj0 = (int)(p0 >> RBITS), d0 = (int)(p0 & (RSZ - 1));
            int sj1 = (int)(p1 >> RBITS), d1 = (int)(p1 & (RSZ - 1));
            int sj2 = (int)(p2 >> RBITS), d2 = (int)(p2 & (RSZ - 1));
            int sj3 = (int)(p3 >> RBITS), d3 = (int)(p3 & (RSZ - 1));
            float xs0 = x[sj0], xs1 = x[sj1], xs2 = x[sj2], xs3 = x[sj3];
            float xd0 = lx[d0], xd1 = lx[d1], xd2 = lx[d2], xd3 = lx[d3];
            float v0 = xs0 * as + xd0 * ad, v1 = xs1 * as + xd1 * ad;
            float v2 = xs2 * as + xd2 * ad, v3 = xs3 * as + xd3 * ad;
            float e0 = __expf(v0 > 0.f ? v0 : NEG_SLOPE * v0);
            float e1 = __expf(v1 > 0.f ? v1 : NEG_SLOPE * v1);
            float e2 = __expf(v2 > 0.f ? v2 : NEG_SLOPE * v2);
            float e3 = __expf(v3 > 0.f ? v3 : NEG_SLOPE * v3);
            u64 u0 = ((u64)(u32)__float2int_rn(e0 * xs0 * NUM_SCALE) << 32) |
                     (u64)(u32)__float2int_rn(e0 * DEN_SCALE);
            u64 u1 = ((u64)(u32)__float2int_rn(e1 * xs1 * NUM_SCALE) << 32) |
                     (u64)(u32)__float2int_rn(e1 * DEN_SCALE);
            u64 u2 = ((u64)(u32)__float2int_rn(e2 * xs2 * NUM_SCALE) << 32) |
                     (u64)(u32)__float2int_rn(e2 * DEN_SCALE);
            u64 u3 = ((u64)(u32)__float2int_rn(e3 * xs3 * NUM_SCALE) << 32) |
                     (u64)(u32)__float2int_rn(e3 * DEN_SCALE);
            atomicAdd(&lacc[d0], u0);
            atomicAdd(&lacc[d1], u1);
            atomicAdd(&lacc[d2], u2);
            atomicAdd(&lacc[d3], u3);
        }
        if (tid < (int)(hi - ahi)) PROC_ONE(src[ahi + tid]);
    }

    // overflow fold-in (normally m == 0: one scalar load + skip)
    u32 m = cnt[MAXNB];
    if (m > 0) {
        if (m > ovfcap) m = ovfcap;
        for (u32 i = (u32)s + (u32)tid * SSUB; i < m; i += (u32)SSUB * P2BLK) {
            u64 p = ovf[i];
            int sj = (int)(p >> 32), dd = (int)(p & 0xFFFFFFFFull);
            if ((dd >> RBITS) == b) {
                int dlow = dd & (RSZ - 1);
                float xs = x[sj];
                float xd = lx[dlow];
                float v = xs * as + xd * ad;
                float logit = v > 0.f ? v : NEG_SLOPE * v;
                float e = __expf(logit);
                u32 den = (u32)__float2int_rn(e * DEN_SCALE);
                int num = __float2int_rn(e * xs * NUM_SCALE);
                atomicAdd(&lacc[dlow], ((u64)(u32)num << 32) | (u64)den);
            }
        }
    }
    __syncthreads();
    u64* dstp = partial + (size_t)blockIdx.x * RSZ;
    #pragma unroll
    for (int r = tid; r < RSZ; r += P2BLK)
        __builtin_nontemporal_store(lacc[r], &dstp[r]);   // consumed next kernel
    #undef PROC_ONE
}

// -------- Phase 3: sum SSUB partials + self-loop, write out --------
__global__ __launch_bounds__(256)
void finalize2(const u64* __restrict__ partial, const float* __restrict__ x,
               const float* __restrict__ att_src_p, const float* __restrict__ att_dst_p,
               const float* __restrict__ bias, float* __restrict__ out, int n) {
    int i = blockIdx.x * blockDim.x + threadIdx.x;
    if (i >= n) return;
    int b = i >> RBITS, r = i & (RSZ - 1);
    const u64* pp = partial + ((size_t)b * SSUB) * RSZ + r;
    u64 t = 0ull;
    #pragma unroll
    for (int s = 0; s < SSUB; ++s) t += pp[(size_t)s * RSZ];
    float xi = x[i];
    float v = xi * (*att_src_p + *att_dst_p);       // self-loop
    float logit = v > 0.f ? v : NEG_SLOPE * v;
    float es = __expf(logit);
    float num = (float)(int)(t >> 32) * INV_NUM_SCALE;
    float den = (float)(u32)(t & 0xFFFFFFFFull) * INV_DEN_SCALE;
    out[i] = (num + es * xi) / (den + es) + *bias;
}

// ================= fallback (ws too small / n too large): far-atomic path ===========
__device__ __forceinline__ void edge_one_dev(float xs, float xd, float as, float ad,
                                             int d, u64* __restrict__ acc) {
    float v = xs * as + xd * ad;
    float logit = v > 0.f ? v : NEG_SLOPE * v;
    float e = __expf(logit);
    u32 den_fx = (u32)__float2int_rn(e * DEN_SCALE);
    int num_fx = __float2int_rn(e * xs * NUM_SCALE);
    atomicAdd(&acc[d], ((u64)(u32)num_fx << 32) | (u64)den_fx);
}

__global__ void edge_accum1(const int* __restrict__ ei, const float* __restrict__ x,
                            const float* __restrict__ att_src_p,
                            const float* __restrict__ att_dst_p,
                            u64* __restrict__ acc, int nedges) {
    int i = blockIdx.x * blockDim.x + threadIdx.x;
    if (i >= nedges) return;
    int s = ei[i], d = ei[nedges + i];
    edge_one_dev(x[s], x[d], *att_src_p, *att_dst_p, d, acc);
}

__global__ void finalize_atomic(const u64* __restrict__ acc, const float* __restrict__ x,
                                const float* __restrict__ att_src_p,
                                const float* __restrict__ att_dst_p,
                                const float* __restrict__ bias, float* __restrict__ out,
                                int n) {
    int i = blockIdx.x * blockDim.x + threadIdx.x;
    if (i >= n) return;
    float xi = x[i];
    float v = xi * (*att_src_p + *att_dst_p);
    float logit = v > 0.f ? v : NEG_SLOPE * v;
    float es = __expf(logit);
    u64 a = acc[i];
    float num = (float)(int)(a >> 32) * INV_NUM_SCALE;
    float den = (float)(u32)(a & 0xFFFFFFFFull) * INV_DEN_SCALE;
    out[i] = (num + es * xi) / (den + es) + *bias;
}

extern "C" void kernel_launch(void* const* d_in, const int* in_sizes, int n_in,
                              void* d_out, int out_size, void* d_ws, size_t ws_size,
                              hipStream_t stream) {
    const float* F       = (const float*)d_in[0];
    const int*   ei      = (const int*)d_in[1];
    const float* W       = (const float*)d_in[2];
    const float* att_src = (const float*)d_in[3];
    const float* att_dst = (const float*)d_in[4];
    const float* bias    = (const float*)d_in[5];
    float* out = (float*)d_out;

    int d = in_sizes[2];              // 512
    int n = in_sizes[0] / d;          // 100000
    int e = in_sizes[1] / 2;          // 6400000

    int nb = (n + RSZ - 1) >> RBITS;  // 25 bins
    // bin capacity: expected + ~6% + fixed slack (>>40 sigma for uniform dst)
    size_t capb_s = ((size_t)e * RSZ) / (size_t)(n > 0 ? n : 1);
    capb_s += capb_s / 16 + 4096;
    int capb = (int)capb_s;
    u32 ovfcap = (u32)e;

    // workspace layout (16B aligned sections; binbuf 16B-aligned for dwordx4 reads)
    size_t off_x   = 0;
    size_t off_cnt = ((size_t)n * 4 + 15) & ~(size_t)15;
    size_t off_par = (off_cnt + (size_t)(MAXNB + 1) * 4 + 15) & ~(size_t)15;
    size_t off_ovf = (off_par + (size_t)nb * SSUB * RSZ * 8 + 15) & ~(size_t)15;
    size_t off_bin = (off_ovf + (size_t)ovfcap * 8 + 15) & ~(size_t)15;
    size_t needed  = off_bin + (size_t)nb * capb_s * 4;

    float* x  = (float*)((char*)d_ws + off_x);
    u32* cnt  = (u32*)((char*)d_ws + off_cnt);
    u64* par  = (u64*)((char*)d_ws + off_par);
    u64* ovf  = (u64*)((char*)d_ws + off_ovf);
    u32* bin  = (u32*)((char*)d_ws + off_bin);

    bool fast = (nb <= MAXNB) && (n <= (1 << (32 - RBITS))) &&
                (needed <= ws_size) && (e > 0) && (n > 0);

    if (fast) {
        // zero only the counters (260 B): bin window cursors + overflow count
        (void)hipMemsetAsync(cnt, 0, (size_t)(MAXNB + 1) * 4, stream);
        int nsblk = (int)(((long long)e + CHUNK - 1) / CHUNK);    // scatter blocks
        int ngblk = (n + 3) / 4;                                  // gemv blocks
        gemv_and_scatter<<<nsblk + ngblk, P1BLK, 0, stream>>>(
            F, W, x, n, d, ei, bin, cnt, ovf, e, nb, capb, nsblk, ovfcap);
        bin_reduce<<<nb * SSUB, P2BLK, 0, stream>>>(bin, cnt, x, ovf, ovfcap,
                                                    att_src, att_dst, par, n, capb);
        finalize2<<<(n + 255) / 256, 256, 0, stream>>>(par, x, att_src, att_dst,
                                                       bias, out, n);
    } else if (n > 0) {
        // fallback: x + single u64 accumulator
        size_t off_acc = ((size_t)n * 4 + 15) & ~(size_t)15;
        u64* acc = (u64*)((char*)d_ws + off_acc);
        (void)hipMemsetAsync(acc, 0, (size_t)n * 8, stream);
        gemv_rowdot<<<(n + 3) / 4, 256, 0, stream>>>(F, W, x, n, d);
        if (e > 0) {
            edge_accum1<<<(e + 255) / 256, 256, 0, stream>>>(ei, x, att_src, att_dst,
                                                             acc, e);
        }
        finalize_atomic<<<(n + 255) / 256, 256, 0, stream>>>(acc, x, att_src, att_dst,
                                                             bias, out, n);
    }
}